// Round 9
// baseline (4906.470 us; speedup 1.0000x reference)
//
#include <hip/hip_runtime.h>
#include <hip/hip_bf16.h>

// LSTM T=1024 B=32 I=H=512.
// Phase 1 (per 128-step chunk): gx = x@Wx^T  (bf16 MFMA, 128x128 tile, fp32 out)
// Phase 2: recurrence, 16 worker blocks pinned to XCD0 (ticket claim + backup).
//   Flagless sentinel protocol:
//   - wave 0 is the sole PUBLISHER (h via LDS hout -> sc0+sc1 stores), never polls
//   - waves 1-7 poll with self-contained rounds: round A = 5x dwordx4 sc0 +
//     vmcnt(0) (fast: same-XCD L2); round B = 5x dwordx4 sc1 + vmcnt(0)
//     (LLC, guaranteed progress). Slots are write-once sentinel->data.
//   - all asm operands are ext_vector types (u32x4), never HIP struct uint4
//   - staging LDS writes lane-contiguous 16B (conflict-free b128); gbuf padded

typedef __attribute__((ext_vector_type(8))) short short8;
typedef __attribute__((ext_vector_type(4))) float f32x4;
typedef __attribute__((ext_vector_type(4))) unsigned u32x4;

#define T_TOT 1024
#define T_CHUNK 128
#define NCHUNK 8
#define BB 32
#define HH 512
#define G4 2048
#define NBLK 16
#define SENT32 0x7F807F80u

__device__ __forceinline__ unsigned short f2bf(float x) {
  union { float f; unsigned u; } v; v.f = x;
  unsigned r = v.u + 0x7FFFu + ((v.u >> 16) & 1u);
  return (unsigned short)(r >> 16);
}

__device__ __forceinline__ float bf2f(unsigned short h) {
  union { unsigned u; float f; } v; v.u = ((unsigned)h) << 16;
  return v.f;
}

__device__ __forceinline__ f32x4 mfma16(short8 a, short8 b, f32x4 c) {
  return __builtin_amdgcn_mfma_f32_16x16x32_bf16(a, b, c, 0, 0, 0);
}

__device__ __forceinline__ unsigned chk4(u32x4 a) {
  return (a.x != SENT32) & (a.y != SENT32) & (a.z != SENT32) & (a.w != SENT32);
}

// ---------------- sentinel fill ----------------
__global__ void fill_sentinel(uint4* __restrict__ p, int n16) {
  int i = blockIdx.x * blockDim.x + threadIdx.x;
  if (i >= n16) return;
  uint4 v; v.x = SENT32; v.y = SENT32; v.z = SENT32; v.w = SENT32;
  p[i] = v;
}

// ---------------- f32 -> bf16 convert ----------------
__global__ void cvt_bf16_kernel(const float* __restrict__ src,
                                unsigned short* __restrict__ dst, int n8) {
  int i = blockIdx.x * blockDim.x + threadIdx.x;
  if (i >= n8) return;
  const float4* s4 = (const float4*)src;
  float4 a = s4[2 * i], b = s4[2 * i + 1];
  short8 o;
  o[0] = (short)f2bf(a.x); o[1] = (short)f2bf(a.y);
  o[2] = (short)f2bf(a.z); o[3] = (short)f2bf(a.w);
  o[4] = (short)f2bf(b.x); o[5] = (short)f2bf(b.y);
  o[6] = (short)f2bf(b.z); o[7] = (short)f2bf(b.w);
  *(short8*)(dst + 8 * i) = o;
}

// ---------------- expand: hseq -> out f32 x2 ----------------
__global__ __launch_bounds__(256) void expand_out(
    const unsigned short* __restrict__ hseq, float* __restrict__ out,
    long long ahO) {
  long long i = (long long)blockIdx.x * blockDim.x + threadIdx.x;
  long long e = i * 8;
  const short8 v = *(const short8*)(hseq + BB * HH + e);  // slot t+1
  float4 lo, hi;
  lo.x = bf2f((unsigned short)v[0]); lo.y = bf2f((unsigned short)v[1]);
  lo.z = bf2f((unsigned short)v[2]); lo.w = bf2f((unsigned short)v[3]);
  hi.x = bf2f((unsigned short)v[4]); hi.y = bf2f((unsigned short)v[5]);
  hi.z = bf2f((unsigned short)v[6]); hi.w = bf2f((unsigned short)v[7]);
  *(float4*)(out + e) = lo;
  *(float4*)(out + e + 4) = hi;
  *(float4*)(out + ahO + e) = lo;
  *(float4*)(out + ahO + e + 4) = hi;
}

__global__ void final_state(const unsigned short* __restrict__ hseq,
                            const float* __restrict__ cbuf,
                            float* __restrict__ out, long long hTO,
                            long long cTO) {
  int i = blockIdx.x * blockDim.x + threadIdx.x;
  if (i >= BB * HH) return;
  out[hTO + i] = bf2f(hseq[(size_t)T_TOT * BB * HH + i]);
  out[cTO + i] = cbuf[i];
}

// ---------------- Phase 1 GEMM ----------------
__global__ __launch_bounds__(256) void gemm_gx(
    const unsigned short* __restrict__ A,
    const unsigned short* __restrict__ Bw,
    float* __restrict__ C)
{
  __shared__ short As[128 * 64];
  __shared__ short Bs[128 * 64];
  const int tid = threadIdx.x;
  const int lane = tid & 63, wave = tid >> 6;
  const int wm = wave >> 1, wn = wave & 1;
  const int m0 = blockIdx.y * 128, n0 = blockIdx.x * 128;
  const int r = lane & 15, kg = lane >> 4;

  const f32x4 vzero = {0.f, 0.f, 0.f, 0.f};
  f32x4 acc[4][4];
#pragma unroll
  for (int i = 0; i < 4; ++i)
#pragma unroll
    for (int j = 0; j < 4; ++j) acc[i][j] = vzero;

  for (int kt = 0; kt < 8; ++kt) {
    const int k0 = kt * 64;
#pragma unroll
    for (int j = 0; j < 4; ++j) {
      int e = j * 2048 + tid * 8;
      int row = e >> 6, col = e & 63;
      *(short8*)(As + e) = *(const short8*)(A + (m0 + row) * 512 + k0 + col);
      *(short8*)(Bs + e) = *(const short8*)(Bw + (n0 + row) * 512 + k0 + col);
    }
    __syncthreads();
#pragma unroll
    for (int ks = 0; ks < 2; ++ks) {
      short8 af[4], bfr[4];
#pragma unroll
      for (int mi = 0; mi < 4; ++mi)
        af[mi] = *(const short8*)(As + (wm * 64 + mi * 16 + r) * 64 + ks * 32 + kg * 8);
#pragma unroll
      for (int ni = 0; ni < 4; ++ni)
        bfr[ni] = *(const short8*)(Bs + (wn * 64 + ni * 16 + r) * 64 + ks * 32 + kg * 8);
#pragma unroll
      for (int mi = 0; mi < 4; ++mi)
#pragma unroll
        for (int ni = 0; ni < 4; ++ni)
          acc[mi][ni] = mfma16(af[mi], bfr[ni], acc[mi][ni]);
    }
    __syncthreads();
  }
  const int cc = lane & 15, rr4 = (lane >> 4) * 4;
#pragma unroll
  for (int mi = 0; mi < 4; ++mi) {
#pragma unroll
    for (int ni = 0; ni < 4; ++ni) {
      int gm = m0 + wm * 64 + mi * 16 + rr4;
      int gn = n0 + wn * 64 + ni * 16 + cc;
#pragma unroll
      for (int j = 0; j < 4; ++j) C[(gm + j) * 2048 + gn] = acc[mi][ni][j];
    }
  }
}

// ---------------- Phase 2: recurrence ----------------
__global__ __launch_bounds__(512, 1) void lstm_seq(
    const float* __restrict__ gx,            // chunk [T_CHUNK][32][2048]
    const unsigned short* __restrict__ Whb,  // [2048][512] bf16
    const float* __restrict__ bias,          // [2048]
    const float* __restrict__ c0,            // [32][512]
    unsigned short* __restrict__ hseq,       // [1025][32][512] bf16, sentinel-filled
    float* __restrict__ cbuf,                // [32][512]
    int* __restrict__ claim,                 // [NCHUNK] ticket counters
    int chunkIdx)
{
  const int tid = threadIdx.x;

  // ---- robust worker claim: XCD0 blocks claim now; others are backups ----
  __shared__ int sg;
  if (tid == 0) {
    unsigned xcc;
    asm volatile("s_getreg_b32 %0, hwreg(HW_REG_XCC_ID)" : "=s"(xcc));
    xcc &= 7u;
    int tk = -1;
    if (xcc == 0) {
      tk = atomicAdd(&claim[chunkIdx], 1);
    } else {
      int cnt = 0;
      for (int i = 0; i < 64; ++i) {
        cnt = __hip_atomic_load(&claim[chunkIdx], __ATOMIC_RELAXED,
                                __HIP_MEMORY_SCOPE_AGENT);
        if (cnt >= NBLK) break;
        __builtin_amdgcn_s_sleep(127);
      }
      if (cnt < NBLK)
        tk = atomicAdd(&claim[chunkIdx], 1);
    }
    sg = tk;
  }
  __syncthreads();
  const int g = sg;
  if (g < 0 || g >= NBLK) return;

  const int t0 = chunkIdx * T_CHUNK;
  const int lane = tid & 63, wave = tid >> 6;
  const int mt = wave >> 2, nt = wave & 3;   // batch half, gate
  const int r = lane & 15, kg = lane >> 4;

  // B fragments: Wh rows for gate nt, units g*32 + ct*16 + r, 16 K-slices
  short8 bfrag[2][16];
#pragma unroll
  for (int ct = 0; ct < 2; ++ct) {
    const int urow = nt * HH + g * 32 + ct * 16 + r;
#pragma unroll
    for (int s = 0; s < 16; ++s)
      bfrag[ct][s] = *(const short8*)((const short*)Whb + urow * HH + s * 32 + kg * 8);
  }
#pragma unroll
  for (int ct = 0; ct < 2; ++ct)
#pragma unroll
    for (int s = 0; s < 16; ++s)
      asm volatile("" : "+v"(bfrag[ct][s]));

  // cell mapping: thread -> (batch b, units u2, u2+1)
  const int b = tid >> 4, u2 = (tid & 15) * 2;
  const int unit0 = g * 32 + u2;
  const float bi0 = bias[0 * HH + unit0], bi1 = bias[0 * HH + unit0 + 1];
  const float bf0 = bias[1 * HH + unit0], bf1 = bias[1 * HH + unit0 + 1];
  const float bg0 = bias[2 * HH + unit0], bg1 = bias[2 * HH + unit0 + 1];
  const float bo0 = bias[3 * HH + unit0], bo1 = bias[3 * HH + unit0 + 1];
  float cst0, cst1;
  if (t0 == 0) { cst0 = c0[b * HH + unit0]; cst1 = c0[b * HH + unit0 + 1]; }
  else         { cst0 = cbuf[b * HH + unit0]; cst1 = cbuf[b * HH + unit0 + 1]; }

  __shared__ unsigned short hs[BB * HH];     // XOR-swizzled h tile (32 KB)
  __shared__ float gbuf[4][BB][33];          // gate pre-acts, padded
  __shared__ unsigned hout2[BB][16];         // packed h pairs (2 KB)

  // staging rows for polling waves (1..7): 5 rows each, rows 0-2 duplicated
  int rows0 = 0, rows1 = 0, rows2 = 0, rows3 = 0, rows4 = 0;
  if (wave >= 1) {
    rows0 = ((wave - 1) * 5 + 0) & 31;
    rows1 = ((wave - 1) * 5 + 1) & 31;
    rows2 = ((wave - 1) * 5 + 2) & 31;
    rows3 = ((wave - 1) * 5 + 3) & 31;
    rows4 = ((wave - 1) * 5 + 4) & 31;
  }
  const int sw0 = (rows0 & 7) << 4, sw1 = (rows1 & 7) << 4,
            sw2 = (rows2 & 7) << 4, sw3 = (rows3 & 7) << 4,
            sw4 = (rows4 & 7) << 4;

  // gx software pipeline: preload step 0
  float2 xi, xf, xg, xo;
  {
    const float* gxp = gx + (long long)b * G4 + unit0;
    xi = *(const float2*)(gxp + 0 * HH);
    xf = *(const float2*)(gxp + 1 * HH);
    xg = *(const float2*)(gxp + 2 * HH);
    xo = *(const float2*)(gxp + 3 * HH);
  }

  for (int tt = 0; tt < T_CHUNK; ++tt) {
    const int t = t0 + tt;

    // ---- POLL phase: waves 1-7 poll + stage h_t; wave 0 skips ----
    if (wave >= 1) {
      const char* hb0 = (const char*)hseq + (size_t)t * (BB * HH * 2) + lane * 16;
      const char* a0 = hb0 + rows0 * 1024;
      const char* a1 = hb0 + rows1 * 1024;
      const char* a2 = hb0 + rows2 * 1024;
      const char* a3 = hb0 + rows3 * 1024;
      const char* a4 = hb0 + rows4 * 1024;
      u32x4 p0, p1, p2, p3, p4;
      unsigned guard = 0;
      while (true) {
        // round A: sc0 (same-XCD L2 fast path), self-contained
        asm volatile(
            "global_load_dwordx4 %0, %5, off sc0\n\t"
            "global_load_dwordx4 %1, %6, off sc0\n\t"
            "global_load_dwordx4 %2, %7, off sc0\n\t"
            "global_load_dwordx4 %3, %8, off sc0\n\t"
            "global_load_dwordx4 %4, %9, off sc0\n\t"
            "s_waitcnt vmcnt(0)"
            : "=&v"(p0), "=&v"(p1), "=&v"(p2), "=&v"(p3), "=&v"(p4)
            : "v"(a0), "v"(a1), "v"(a2), "v"(a3), "v"(a4)
            : "memory");
        if (chk4(p0) & chk4(p1) & chk4(p2) & chk4(p3) & chk4(p4)) break;
        if (++guard > 4096) break;
        // round B: sc1 (LLC, guaranteed progress), self-contained
        asm volatile(
            "global_load_dwordx4 %0, %5, off sc1\n\t"
            "global_load_dwordx4 %1, %6, off sc1\n\t"
            "global_load_dwordx4 %2, %7, off sc1\n\t"
            "global_load_dwordx4 %3, %8, off sc1\n\t"
            "global_load_dwordx4 %4, %9, off sc1\n\t"
            "s_waitcnt vmcnt(0)"
            : "=&v"(p0), "=&v"(p1), "=&v"(p2), "=&v"(p3), "=&v"(p4)
            : "v"(a0), "v"(a1), "v"(a2), "v"(a3), "v"(a4)
            : "memory");
        if (chk4(p0) & chk4(p1) & chk4(p2) & chk4(p3) & chk4(p4)) break;
        if (++guard > 4096) break;
      }
      // conflict-free staged LDS writes (lane-contiguous 16B beats)
      const int lb = lane * 16;
      *(u32x4*)((char*)hs + ((rows0 * 1024 + lb) ^ sw0)) = p0;
      *(u32x4*)((char*)hs + ((rows1 * 1024 + lb) ^ sw1)) = p1;
      *(u32x4*)((char*)hs + ((rows2 * 1024 + lb) ^ sw2)) = p2;
      *(u32x4*)((char*)hs + ((rows3 * 1024 + lb) ^ sw3)) = p3;
      *(u32x4*)((char*)hs + ((rows4 * 1024 + lb) ^ sw4)) = p4;
    }
    __syncthreads();   // B1: h staged

    // ---- prefetch next step's gx ----
    float2 nxi, nxf, nxg, nxo;
    {
      const int tn = (tt + 1 < T_CHUNK) ? tt + 1 : tt;
      const float* gxp = gx + (long long)tn * BB * G4 + b * G4 + unit0;
      nxi = *(const float2*)(gxp + 0 * HH);
      nxf = *(const float2*)(gxp + 1 * HH);
      nxg = *(const float2*)(gxp + 2 * HH);
      nxo = *(const float2*)(gxp + 3 * HH);
    }

    // MFMA: gate nt, batches mt*16..+16, 2 col-tiles of 16
    f32x4 aE0 = {0, 0, 0, 0}, aO0 = {0, 0, 0, 0};
    f32x4 aE1 = {0, 0, 0, 0}, aO1 = {0, 0, 0, 0};
    const int abase = (mt * 16 + r) * 1024;
    const int aswz = (r & 7) << 4;
#pragma unroll
    for (int s = 0; s < 16; s += 2) {
      short8 a0f = *(const short8*)((const char*)hs + ((abase + s * 64 + kg * 16) ^ aswz));
      short8 a1f = *(const short8*)((const char*)hs + ((abase + (s + 1) * 64 + kg * 16) ^ aswz));
      aE0 = mfma16(a0f, bfrag[0][s], aE0);
      aE1 = mfma16(a0f, bfrag[1][s], aE1);
      aO0 = mfma16(a1f, bfrag[0][s + 1], aO0);
      aO1 = mfma16(a1f, bfrag[1][s + 1], aO1);
    }
    const f32x4 acc0 = aE0 + aO0, acc1 = aE1 + aO1;
#pragma unroll
    for (int j = 0; j < 4; ++j) {
      gbuf[nt][mt * 16 + kg * 4 + j][r] = acc0[j];
      gbuf[nt][mt * 16 + kg * 4 + j][16 + r] = acc1[j];
    }
    __syncthreads();   // B2

    // cell update: 2 cells
    float gi0 = gbuf[0][b][u2] + xi.x + bi0, gi1 = gbuf[0][b][u2 + 1] + xi.y + bi1;
    float gf0_ = gbuf[1][b][u2] + xf.x + bf0, gf1_ = gbuf[1][b][u2 + 1] + xf.y + bf1;
    float gg0 = gbuf[2][b][u2] + xg.x + bg0, gg1 = gbuf[2][b][u2 + 1] + xg.y + bg1;
    float go0 = gbuf[3][b][u2] + xo.x + bo0, go1 = gbuf[3][b][u2 + 1] + xo.y + bo1;
    float si0 = 1.f / (1.f + __expf(-gi0)), si1 = 1.f / (1.f + __expf(-gi1));
    float sf0 = 1.f / (1.f + __expf(-gf0_)), sf1 = 1.f / (1.f + __expf(-gf1_));
    float so0 = 1.f / (1.f + __expf(-go0)), so1 = 1.f / (1.f + __expf(-go1));
    float tg0 = 2.f / (1.f + __expf(-2.f * gg0)) - 1.f;
    float tg1 = 2.f / (1.f + __expf(-2.f * gg1)) - 1.f;
    cst0 = sf0 * cst0 + si0 * tg0;
    cst1 = sf1 * cst1 + si1 * tg1;
    float tc0 = 2.f / (1.f + __expf(-2.f * cst0)) - 1.f;
    float tc1 = 2.f / (1.f + __expf(-2.f * cst1)) - 1.f;
    float hn0 = so0 * tc0, hn1 = so1 * tc1;

    // h pair -> LDS hout
    hout2[b][u2 >> 1] = (unsigned)f2bf(hn0) | ((unsigned)f2bf(hn1) << 16);
    __syncthreads();   // B3: hout complete

    // ---- PUBLISH phase: wave 0 only ----
    if (wave == 0) {
      const int prow = lane >> 1, phalf = lane & 1;
      const unsigned* hr = &hout2[prow][phalf * 8];
      u32x4 ha = *(const u32x4*)hr;
      u32x4 hb2 = *(const u32x4*)(hr + 4);
      char* pa = (char*)hseq + (size_t)(t + 1) * (BB * HH * 2) +
                 (size_t)prow * 1024 + g * 64 + phalf * 32;
      asm volatile(
          "global_store_dwordx4 %0, %1, off sc0\n\t"
          "global_store_dwordx4 %0, %2, off offset:16 sc0\n\t"
          "global_store_dwordx4 %0, %1, off sc1\n\t"
          "global_store_dwordx4 %0, %2, off offset:16 sc1"
          :: "v"(pa), "v"(ha), "v"(hb2) : "memory");
    }

    xi = nxi; xf = nxf; xg = nxg; xo = nxo;

    if (tt == T_CHUNK - 1) {
      cbuf[b * HH + unit0] = cst0;
      cbuf[b * HH + unit0 + 1] = cst1;
    }
  }
}

extern "C" void kernel_launch(void* const* d_in, const int* in_sizes, int n_in,
                              void* d_out, int out_size, void* d_ws, size_t ws_size,
                              hipStream_t stream) {
  const float* x  = (const float*)d_in[0];
  const float* h0 = (const float*)d_in[1];
  const float* c0 = (const float*)d_in[2];
  const float* Wx = (const float*)d_in[3];
  const float* Wh = (const float*)d_in[4];
  const float* b  = (const float*)d_in[5];
  float* out = (float*)d_out;
  char* ws = (char*)d_ws;

  // ws layout (~100.2 MB)
  float* gx            = (float*)ws;                            // 32 MiB
  unsigned short* xb   = (unsigned short*)(ws + 33554432);      // 32 MiB (full x, bf16)
  unsigned short* Wxb  = (unsigned short*)(ws + 67108864);      // 2 MiB
  unsigned short* Whb  = (unsigned short*)(ws + 69206016);      // 2 MiB
  unsigned short* hseq = (unsigned short*)(ws + 71303168);      // 1025*32KB
  float* cbuf          = (float*)(ws + 104923136);              // 64 KiB
  int* claim           = (int*)(ws + 104988672);                // 32 B

  const long long hTO = (long long)T_TOT * BB * HH;
  const long long cTO = hTO + BB * HH;
  const long long ahO = cTO + BB * HH;

  (void)hipMemsetAsync(claim, 0, NCHUNK * sizeof(int), stream);

  // sentinel-fill hseq (every call -> deterministic across replays)
  const int n16 = (1025 * BB * HH * 2) / 16;
  fill_sentinel<<<(n16 + 255) / 256, 256, 0, stream>>>((uint4*)hseq, n16);

  // converts: x, Wx, Wh -> bf16; h0 -> hseq slot 0 (after fill)
  cvt_bf16_kernel<<<8192, 256, 0, stream>>>(x, xb, 16777216 / 8);
  cvt_bf16_kernel<<<512, 256, 0, stream>>>(Wx, Wxb, 1048576 / 8);
  cvt_bf16_kernel<<<512, 256, 0, stream>>>(Wh, Whb, 1048576 / 8);
  cvt_bf16_kernel<<<8, 256, 0, stream>>>(h0, hseq, 16384 / 8);

  for (int ch = 0; ch < NCHUNK; ++ch) {
    gemm_gx<<<dim3(16, 32), 256, 0, stream>>>(xb + (size_t)ch * 4096 * 512, Wxb, gx);
    lstm_seq<<<256, 512, 0, stream>>>(gx, Whb, b, c0, hseq, cbuf, claim, ch);
  }

  // post-pass: materialize d_out from hseq (+ final c)
  expand_out<<<8192, 256, 0, stream>>>(hseq, out, ahO);
  final_state<<<64, 256, 0, stream>>>(hseq, cbuf, out, hTO, cTO);
}

// Round 10
// 2640.046 us; speedup vs baseline: 1.8585x; 1.8585x over previous
//
#include <hip/hip_runtime.h>
#include <hip/hip_bf16.h>

// LSTM T=1024 B=32 I=H=512.
// Phase 1 (per 128-step chunk): gx = x@Wx^T  (bf16 MFMA, 128x128 tile, fp32 out)
// Phase 2: recurrence, 16 worker blocks pinned to XCD0 (ticket claim + backup).
//   R5-style flagless sentinel protocol (best measured): per-thread sc1 u32
//   publish direct from cell; ALL waves poll+stage. This round: batched asm
//   sc1 poll (4x dwordx4 + one vmcnt), gx prefetched AFTER poll (off the
//   critical vmcnt), conflict-free interleaved staging, padded gbuf.

typedef __attribute__((ext_vector_type(8))) short short8;
typedef __attribute__((ext_vector_type(4))) float f32x4;
typedef __attribute__((ext_vector_type(4))) unsigned u32x4;

#define T_TOT 1024
#define T_CHUNK 128
#define NCHUNK 8
#define BB 32
#define HH 512
#define G4 2048
#define NBLK 16
#define SENT32 0x7F807F80u

__device__ __forceinline__ unsigned short f2bf(float x) {
  union { float f; unsigned u; } v; v.f = x;
  unsigned r = v.u + 0x7FFFu + ((v.u >> 16) & 1u);
  return (unsigned short)(r >> 16);
}

__device__ __forceinline__ float bf2f(unsigned short h) {
  union { unsigned u; float f; } v; v.u = ((unsigned)h) << 16;
  return v.f;
}

__device__ __forceinline__ f32x4 mfma16(short8 a, short8 b, f32x4 c) {
  return __builtin_amdgcn_mfma_f32_16x16x32_bf16(a, b, c, 0, 0, 0);
}

__device__ __forceinline__ unsigned chk4(u32x4 a) {
  return (a.x != SENT32) & (a.y != SENT32) & (a.z != SENT32) & (a.w != SENT32);
}

// ---------------- sentinel fill ----------------
__global__ void fill_sentinel(uint4* __restrict__ p, int n16) {
  int i = blockIdx.x * blockDim.x + threadIdx.x;
  if (i >= n16) return;
  uint4 v; v.x = SENT32; v.y = SENT32; v.z = SENT32; v.w = SENT32;
  p[i] = v;
}

// ---------------- f32 -> bf16 convert ----------------
__global__ void cvt_bf16_kernel(const float* __restrict__ src,
                                unsigned short* __restrict__ dst, int n8) {
  int i = blockIdx.x * blockDim.x + threadIdx.x;
  if (i >= n8) return;
  const float4* s4 = (const float4*)src;
  float4 a = s4[2 * i], b = s4[2 * i + 1];
  short8 o;
  o[0] = (short)f2bf(a.x); o[1] = (short)f2bf(a.y);
  o[2] = (short)f2bf(a.z); o[3] = (short)f2bf(a.w);
  o[4] = (short)f2bf(b.x); o[5] = (short)f2bf(b.y);
  o[6] = (short)f2bf(b.z); o[7] = (short)f2bf(b.w);
  *(short8*)(dst + 8 * i) = o;
}

// ---------------- expand: hseq -> out f32 x2 ----------------
__global__ __launch_bounds__(256) void expand_out(
    const unsigned short* __restrict__ hseq, float* __restrict__ out,
    long long ahO) {
  long long i = (long long)blockIdx.x * blockDim.x + threadIdx.x;
  long long e = i * 8;
  const short8 v = *(const short8*)(hseq + BB * HH + e);  // slot t+1
  float4 lo, hi;
  lo.x = bf2f((unsigned short)v[0]); lo.y = bf2f((unsigned short)v[1]);
  lo.z = bf2f((unsigned short)v[2]); lo.w = bf2f((unsigned short)v[3]);
  hi.x = bf2f((unsigned short)v[4]); hi.y = bf2f((unsigned short)v[5]);
  hi.z = bf2f((unsigned short)v[6]); hi.w = bf2f((unsigned short)v[7]);
  *(float4*)(out + e) = lo;
  *(float4*)(out + e + 4) = hi;
  *(float4*)(out + ahO + e) = lo;
  *(float4*)(out + ahO + e + 4) = hi;
}

__global__ void final_state(const unsigned short* __restrict__ hseq,
                            const float* __restrict__ cbuf,
                            float* __restrict__ out, long long hTO,
                            long long cTO) {
  int i = blockIdx.x * blockDim.x + threadIdx.x;
  if (i >= BB * HH) return;
  out[hTO + i] = bf2f(hseq[(size_t)T_TOT * BB * HH + i]);
  out[cTO + i] = cbuf[i];
}

// ---------------- Phase 1 GEMM ----------------
__global__ __launch_bounds__(256) void gemm_gx(
    const unsigned short* __restrict__ A,
    const unsigned short* __restrict__ Bw,
    float* __restrict__ C)
{
  __shared__ short As[128 * 64];
  __shared__ short Bs[128 * 64];
  const int tid = threadIdx.x;
  const int lane = tid & 63, wave = tid >> 6;
  const int wm = wave >> 1, wn = wave & 1;
  const int m0 = blockIdx.y * 128, n0 = blockIdx.x * 128;
  const int r = lane & 15, kg = lane >> 4;

  const f32x4 vzero = {0.f, 0.f, 0.f, 0.f};
  f32x4 acc[4][4];
#pragma unroll
  for (int i = 0; i < 4; ++i)
#pragma unroll
    for (int j = 0; j < 4; ++j) acc[i][j] = vzero;

  for (int kt = 0; kt < 8; ++kt) {
    const int k0 = kt * 64;
#pragma unroll
    for (int j = 0; j < 4; ++j) {
      int e = j * 2048 + tid * 8;
      int row = e >> 6, col = e & 63;
      *(short8*)(As + e) = *(const short8*)(A + (m0 + row) * 512 + k0 + col);
      *(short8*)(Bs + e) = *(const short8*)(Bw + (n0 + row) * 512 + k0 + col);
    }
    __syncthreads();
#pragma unroll
    for (int ks = 0; ks < 2; ++ks) {
      short8 af[4], bfr[4];
#pragma unroll
      for (int mi = 0; mi < 4; ++mi)
        af[mi] = *(const short8*)(As + (wm * 64 + mi * 16 + r) * 64 + ks * 32 + kg * 8);
#pragma unroll
      for (int ni = 0; ni < 4; ++ni)
        bfr[ni] = *(const short8*)(Bs + (wn * 64 + ni * 16 + r) * 64 + ks * 32 + kg * 8);
#pragma unroll
      for (int mi = 0; mi < 4; ++mi)
#pragma unroll
        for (int ni = 0; ni < 4; ++ni)
          acc[mi][ni] = mfma16(af[mi], bfr[ni], acc[mi][ni]);
    }
    __syncthreads();
  }
  const int cc = lane & 15, rr4 = (lane >> 4) * 4;
#pragma unroll
  for (int mi = 0; mi < 4; ++mi) {
#pragma unroll
    for (int ni = 0; ni < 4; ++ni) {
      int gm = m0 + wm * 64 + mi * 16 + rr4;
      int gn = n0 + wn * 64 + ni * 16 + cc;
#pragma unroll
      for (int j = 0; j < 4; ++j) C[(gm + j) * 2048 + gn] = acc[mi][ni][j];
    }
  }
}

// ---------------- Phase 2: recurrence ----------------
__global__ __launch_bounds__(512, 1) void lstm_seq(
    const float* __restrict__ gx,            // chunk [T_CHUNK][32][2048]
    const unsigned short* __restrict__ Whb,  // [2048][512] bf16
    const float* __restrict__ bias,          // [2048]
    const float* __restrict__ c0,            // [32][512]
    unsigned short* __restrict__ hseq,       // [1025][32][512] bf16, sentinel-filled
    float* __restrict__ cbuf,                // [32][512]
    int* __restrict__ claim,                 // [NCHUNK] ticket counters
    int chunkIdx)
{
  const int tid = threadIdx.x;

  // ---- worker claim: XCD0 blocks claim now; others are backups ----
  __shared__ int sg;
  if (tid == 0) {
    unsigned xcc;
    asm volatile("s_getreg_b32 %0, hwreg(HW_REG_XCC_ID)" : "=s"(xcc));
    xcc &= 7u;
    int tk = -1;
    if (xcc == 0) {
      tk = atomicAdd(&claim[chunkIdx], 1);
    } else {
      int cnt = 0;
      for (int i = 0; i < 64; ++i) {
        cnt = __hip_atomic_load(&claim[chunkIdx], __ATOMIC_RELAXED,
                                __HIP_MEMORY_SCOPE_AGENT);
        if (cnt >= NBLK) break;
        __builtin_amdgcn_s_sleep(127);
      }
      if (cnt < NBLK)
        tk = atomicAdd(&claim[chunkIdx], 1);
    }
    sg = tk;
  }
  __syncthreads();
  const int g = sg;
  if (g < 0 || g >= NBLK) return;

  const int t0 = chunkIdx * T_CHUNK;
  const int lane = tid & 63, wave = tid >> 6;
  const int mt = wave >> 2, nt = wave & 3;   // batch half, gate
  const int r = lane & 15, kg = lane >> 4;

  // B fragments: Wh rows for gate nt, units g*32 + ct*16 + r, 16 K-slices
  short8 bfrag[2][16];
#pragma unroll
  for (int ct = 0; ct < 2; ++ct) {
    const int urow = nt * HH + g * 32 + ct * 16 + r;
#pragma unroll
    for (int s = 0; s < 16; ++s)
      bfrag[ct][s] = *(const short8*)((const short*)Whb + urow * HH + s * 32 + kg * 8);
  }
#pragma unroll
  for (int ct = 0; ct < 2; ++ct)
#pragma unroll
    for (int s = 0; s < 16; ++s)
      asm volatile("" : "+v"(bfrag[ct][s]));

  // cell mapping: thread -> (batch b, units u2, u2+1)
  const int b = tid >> 4, u2 = (tid & 15) * 2;
  const int unit0 = g * 32 + u2;
  const float bi0 = bias[0 * HH + unit0], bi1 = bias[0 * HH + unit0 + 1];
  const float bf0 = bias[1 * HH + unit0], bf1 = bias[1 * HH + unit0 + 1];
  const float bg0 = bias[2 * HH + unit0], bg1 = bias[2 * HH + unit0 + 1];
  const float bo0 = bias[3 * HH + unit0], bo1 = bias[3 * HH + unit0 + 1];
  float cst0, cst1;
  if (t0 == 0) { cst0 = c0[b * HH + unit0]; cst1 = c0[b * HH + unit0 + 1]; }
  else         { cst0 = cbuf[b * HH + unit0]; cst1 = cbuf[b * HH + unit0 + 1]; }

  __shared__ unsigned short hs[BB * HH];     // XOR-swizzled h tile (32 KB)
  __shared__ float gbuf[4][BB][33];          // gate pre-acts, padded

  // staging: thread = row tid>>4, bytes (tid&15)*16 + k*256 (k=0..3)
  const int srow = tid >> 4;
  const int sb = (tid & 15) * 16;
  const int sswz = (srow & 7) << 4;

  // gx pipeline: preload step 0
  float2 xi, xf, xg, xo;
  {
    const float* gxp = gx + (long long)b * G4 + unit0;
    xi = *(const float2*)(gxp + 0 * HH);
    xf = *(const float2*)(gxp + 1 * HH);
    xg = *(const float2*)(gxp + 2 * HH);
    xo = *(const float2*)(gxp + 3 * HH);
  }

  for (int tt = 0; tt < T_CHUNK; ++tt) {
    const int t = t0 + tt;

    // ---- batched sc1 sentinel poll of h_t (one vmcnt RT per round) ----
    const char* hqb = (const char*)hseq + (size_t)t * (BB * HH * 2) +
                      (size_t)srow * 1024 + sb;
    u32x4 p0, p1, p2, p3;
    {
      unsigned guard = 0;
      while (true) {
        asm volatile(
            "global_load_dwordx4 %0, %4, off sc1\n\t"
            "global_load_dwordx4 %1, %4, off offset:256 sc1\n\t"
            "global_load_dwordx4 %2, %4, off offset:512 sc1\n\t"
            "global_load_dwordx4 %3, %4, off offset:768 sc1\n\t"
            "s_waitcnt vmcnt(0)"
            : "=&v"(p0), "=&v"(p1), "=&v"(p2), "=&v"(p3)
            : "v"(hqb)
            : "memory");
        if (chk4(p0) & chk4(p1) & chk4(p2) & chk4(p3)) break;
        if (++guard > 8192) break;
      }
    }
    // conflict-free staged LDS writes (verified 2-way max)
    {
      const int base = srow * 1024 + sb;
      *(u32x4*)((char*)hs + ((base + 0) ^ sswz)) = p0;
      *(u32x4*)((char*)hs + ((base + 256) ^ sswz)) = p1;
      *(u32x4*)((char*)hs + ((base + 512) ^ sswz)) = p2;
      *(u32x4*)((char*)hs + ((base + 768) ^ sswz)) = p3;
    }

    // ---- prefetch next step's gx NOW (hides under B1+MFMA+cell+publish) ----
    float2 nxi, nxf, nxg, nxo;
    {
      const int tn = (tt + 1 < T_CHUNK) ? tt + 1 : tt;
      const float* gxp = gx + (long long)tn * BB * G4 + b * G4 + unit0;
      nxi = *(const float2*)(gxp + 0 * HH);
      nxf = *(const float2*)(gxp + 1 * HH);
      nxg = *(const float2*)(gxp + 2 * HH);
      nxo = *(const float2*)(gxp + 3 * HH);
    }
    __syncthreads();   // B1: h staged

    // MFMA: gate nt, batches mt*16..+16, 2 col-tiles of 16
    f32x4 aE0 = {0, 0, 0, 0}, aO0 = {0, 0, 0, 0};
    f32x4 aE1 = {0, 0, 0, 0}, aO1 = {0, 0, 0, 0};
    const int abase = (mt * 16 + r) * 1024;
    const int aswz = (r & 7) << 4;
#pragma unroll
    for (int s = 0; s < 16; s += 2) {
      short8 a0f = *(const short8*)((const char*)hs + ((abase + s * 64 + kg * 16) ^ aswz));
      short8 a1f = *(const short8*)((const char*)hs + ((abase + (s + 1) * 64 + kg * 16) ^ aswz));
      aE0 = mfma16(a0f, bfrag[0][s], aE0);
      aE1 = mfma16(a0f, bfrag[1][s], aE1);
      aO0 = mfma16(a1f, bfrag[0][s + 1], aO0);
      aO1 = mfma16(a1f, bfrag[1][s + 1], aO1);
    }
    const f32x4 acc0 = aE0 + aO0, acc1 = aE1 + aO1;
#pragma unroll
    for (int j = 0; j < 4; ++j) {
      gbuf[nt][mt * 16 + kg * 4 + j][r] = acc0[j];
      gbuf[nt][mt * 16 + kg * 4 + j][16 + r] = acc1[j];
    }
    __syncthreads();   // B2

    // cell update: 2 cells
    float gi0 = gbuf[0][b][u2] + xi.x + bi0, gi1 = gbuf[0][b][u2 + 1] + xi.y + bi1;
    float gf0_ = gbuf[1][b][u2] + xf.x + bf0, gf1_ = gbuf[1][b][u2 + 1] + xf.y + bf1;
    float gg0 = gbuf[2][b][u2] + xg.x + bg0, gg1 = gbuf[2][b][u2 + 1] + xg.y + bg1;
    float go0 = gbuf[3][b][u2] + xo.x + bo0, go1 = gbuf[3][b][u2 + 1] + xo.y + bo1;
    float si0 = 1.f / (1.f + __expf(-gi0)), si1 = 1.f / (1.f + __expf(-gi1));
    float sf0 = 1.f / (1.f + __expf(-gf0_)), sf1 = 1.f / (1.f + __expf(-gf1_));
    float so0 = 1.f / (1.f + __expf(-go0)), so1 = 1.f / (1.f + __expf(-go1));
    float tg0 = 2.f / (1.f + __expf(-2.f * gg0)) - 1.f;
    float tg1 = 2.f / (1.f + __expf(-2.f * gg1)) - 1.f;
    cst0 = sf0 * cst0 + si0 * tg0;
    cst1 = sf1 * cst1 + si1 * tg1;
    float tc0 = 2.f / (1.f + __expf(-2.f * cst0)) - 1.f;
    float tc1 = 2.f / (1.f + __expf(-2.f * cst1)) - 1.f;
    float hn0 = so0 * tc0, hn1 = so1 * tc1;

    // publish h_{t+1}: per-thread u32 sc1 store direct from cell (R5-proven)
    unsigned w32 = (unsigned)f2bf(hn0) | ((unsigned)f2bf(hn1) << 16);
    char* pa = (char*)hseq + (size_t)(t + 1) * (BB * HH * 2) +
               (size_t)(b * HH + unit0) * 2;
    asm volatile("global_store_dword %0, %1, off sc1"
                 :: "v"(pa), "v"(w32) : "memory");

    xi = nxi; xf = nxf; xg = nxg; xo = nxo;

    if (tt == T_CHUNK - 1) {
      cbuf[b * HH + unit0] = cst0;
      cbuf[b * HH + unit0 + 1] = cst1;
    }
  }
}

extern "C" void kernel_launch(void* const* d_in, const int* in_sizes, int n_in,
                              void* d_out, int out_size, void* d_ws, size_t ws_size,
                              hipStream_t stream) {
  const float* x  = (const float*)d_in[0];
  const float* h0 = (const float*)d_in[1];
  const float* c0 = (const float*)d_in[2];
  const float* Wx = (const float*)d_in[3];
  const float* Wh = (const float*)d_in[4];
  const float* b  = (const float*)d_in[5];
  float* out = (float*)d_out;
  char* ws = (char*)d_ws;

  // ws layout (~100.2 MB)
  float* gx            = (float*)ws;                            // 32 MiB
  unsigned short* xb   = (unsigned short*)(ws + 33554432);      // 32 MiB (full x, bf16)
  unsigned short* Wxb  = (unsigned short*)(ws + 67108864);      // 2 MiB
  unsigned short* Whb  = (unsigned short*)(ws + 69206016);      // 2 MiB
  unsigned short* hseq = (unsigned short*)(ws + 71303168);      // 1025*32KB
  float* cbuf          = (float*)(ws + 104923136);              // 64 KiB
  int* claim           = (int*)(ws + 104988672);                // 32 B

  const long long hTO = (long long)T_TOT * BB * HH;
  const long long cTO = hTO + BB * HH;
  const long long ahO = cTO + BB * HH;

  (void)hipMemsetAsync(claim, 0, NCHUNK * sizeof(int), stream);

  // sentinel-fill hseq (every call -> deterministic across replays)
  const int n16 = (1025 * BB * HH * 2) / 16;
  fill_sentinel<<<(n16 + 255) / 256, 256, 0, stream>>>((uint4*)hseq, n16);

  // converts: x, Wx, Wh -> bf16; h0 -> hseq slot 0 (after fill)
  cvt_bf16_kernel<<<8192, 256, 0, stream>>>(x, xb, 16777216 / 8);
  cvt_bf16_kernel<<<512, 256, 0, stream>>>(Wx, Wxb, 1048576 / 8);
  cvt_bf16_kernel<<<512, 256, 0, stream>>>(Wh, Whb, 1048576 / 8);
  cvt_bf16_kernel<<<8, 256, 0, stream>>>(h0, hseq, 16384 / 8);

  for (int ch = 0; ch < NCHUNK; ++ch) {
    gemm_gx<<<dim3(16, 32), 256, 0, stream>>>(xb + (size_t)ch * 4096 * 512, Wxb, gx);
    lstm_seq<<<256, 512, 0, stream>>>(gx, Whb, b, c0, hseq, cbuf, claim, ch);
  }

  // post-pass: materialize d_out from hseq (+ final c)
  expand_out<<<8192, 256, 0, stream>>>(hseq, out, ahO);
  final_state<<<64, 256, 0, stream>>>(hseq, cbuf, out, hTO, cTO);
}